// Round 1
// baseline (1979.824 us; speedup 1.0000x reference)
//
#include <hip/hip_runtime.h>
#include <math.h>

#define NROWS 16384
#define MINN 1e-15f
#define NITER (NROWS / 1024)

typedef float vf4 __attribute__((ext_vector_type(4)));

__device__ __forceinline__ float waveSum(float v) {
    #pragma unroll
    for (int m = 32; m >= 1; m >>= 1) v += __shfl_xor(v, m, 64);
    return v;
}

// Recompute ht[j] = logmap0(proj(expmap0(logmap0(x_j) @ W^T))) for row j.
// Identical op sequence to the old prep_kernel -> bitwise-identical values.
__device__ __forceinline__ float compute_ht(
    const float* __restrict__ x, const float* WT, int j, int lane)
{
    float xv = x[(size_t)j * 64 + lane];
    // u = logmap0(x_j)
    float sq = (lane == 0) ? 0.f : xv * xv;
    float yn = fmaxf(sqrtf(waveSum(sq)), MINN);
    float theta = fmaxf(__shfl(xv, 0, 64), 1.0f + 1e-7f);
    float s = acoshf(theta) / yn;
    float u = (lane == 0) ? 0.f : s * xv;

    // h1[k] = sum_d u[d] * W[k][d]  (lane = k); u[0]==0 so start at d=1
    float h1 = 0.f;
    #pragma unroll
    for (int d = 1; d < 64; ++d)
        h1 = fmaf(__shfl(u, d, 64), WT[d * 64 + lane], h1);

    // ht = logmap0(proj(expmap0(h1)))
    float z = (lane == 0) ? 0.f : h1;
    float zn = fmaxf(sqrtf(waveSum(z * z)), MINN);
    float sh = sinhf(zn);
    float ey = sh * z / zn;                       // lane0 -> 0
    float s2 = waveSum(ey * ey);
    float first = sqrtf(fmaxf(1.f + s2, MINN));
    float ynb = fmaxf(sqrtf(s2), MINN);
    float th2 = fmaxf(first, 1.0f + 1e-7f);
    float coef = acoshf(th2) / ynb;
    return (lane == 0) ? 0.f : coef * ey;
}

// Fully fused: one wave per output row. Streams the adj row (prefetched one
// iteration deep), recomputes ht[j] per discovered neighbor (no workspace),
// then applies the fused epilogue. d_ws is never touched.
__global__ __launch_bounds__(256) void fused_kernel(
    const float* __restrict__ x, const float* __restrict__ adj,
    const float* __restrict__ W, float* __restrict__ out)
{
    const int lane = threadIdx.x & 63;
    const int row = blockIdx.x * 4 + (threadIdx.x >> 6);
    const float* arow = adj + (size_t)row * NROWS;

    // Issue first adj window before staging W (independent of LDS).
    const float* b0 = arow + lane * 4;
    vf4 c0 = __builtin_nontemporal_load((const vf4*)(b0 + 0));
    vf4 c1 = __builtin_nontemporal_load((const vf4*)(b0 + 256));
    vf4 c2 = __builtin_nontemporal_load((const vf4*)(b0 + 512));
    vf4 c3 = __builtin_nontemporal_load((const vf4*)(b0 + 768));

    __shared__ float WT[64 * 64];
    for (int t = threadIdx.x; t < 64 * 64; t += 256) {
        int k = t >> 6, d = t & 63;
        WT[d * 64 + k] = W[t];   // broadcast reads later -> conflict-free
    }
    __syncthreads();

    float acc = 0.f;
    for (int it = 0; it < NITER; ++it) {
        vf4 n0, n1, n2, n3;
        const bool more = (it + 1 < NITER);
        if (more) {
            const float* nb = arow + (size_t)(it + 1) * 1024 + lane * 4;
            n0 = __builtin_nontemporal_load((const vf4*)(nb + 0));
            n1 = __builtin_nontemporal_load((const vf4*)(nb + 256));
            n2 = __builtin_nontemporal_load((const vf4*)(nb + 512));
            n3 = __builtin_nontemporal_load((const vf4*)(nb + 768));
        }
        #pragma unroll
        for (int w = 0; w < 4; ++w) {
            vf4 v = (w == 0) ? c0 : (w == 1) ? c1 : (w == 2) ? c2 : c3;
            unsigned int any = __float_as_uint(v.x) | __float_as_uint(v.y) |
                               __float_as_uint(v.z) | __float_as_uint(v.w);
            unsigned long long mask = __ballot(any != 0u);  // zeros are exact +0.0
            int jwin = it * 1024 + w * 256;
            while (mask) {
                int L = __ffsll((long long)mask) - 1;
                mask &= mask - 1;
                float a0 = __shfl(v.x, L, 64);
                float a1 = __shfl(v.y, L, 64);
                float a2 = __shfl(v.z, L, 64);
                float a3 = __shfl(v.w, L, 64);
                int jbase = jwin + L * 4;
                // unroll 1: single inlined compute_ht per w-case (code size)
                #pragma unroll 1
                for (int q = 0; q < 4; ++q) {
                    float aq = (q == 0) ? a0 : (q == 1) ? a1 : (q == 2) ? a2 : a3;
                    if (aq != 0.f)
                        acc = fmaf(aq, compute_ht(x, WT, jbase + q, lane), acc);
                }
            }
        }
        if (more) { c0 = n0; c1 = n1; c2 = n2; c3 = n3; }
    }

    // Epilogue (literal reference clamps; empty rows -> [1,0,...,0])
    float z = (lane == 0) ? 0.f : acc;
    float zn = fmaxf(sqrtf(waveSum(z * z)), MINN);
    float sh = sinhf(zn);
    float ey = sh * z / zn;
    float s2 = waveSum(ey * ey);
    float first = sqrtf(fmaxf(1.f + s2, MINN));
    float ynb = fmaxf(sqrtf(s2), MINN);
    float th2 = fmaxf(first, 1.0f + 1e-7f);
    float l = acoshf(th2) / ynb * ey;
    float xt = fmaxf(l, 0.f);
    if (lane == 0) xt = 0.f;
    float xn = fmaxf(sqrtf(waveSum(xt * xt)), MINN);
    float sh2 = sinhf(xn);
    float oy = sh2 * xt / xn;
    float o0 = sqrtf(fmaxf(1.f + waveSum(oy * oy), MINN));
    float outv = (lane == 0) ? o0 : oy;
    out[row * 64 + lane] = outv;
}

extern "C" void kernel_launch(void* const* d_in, const int* in_sizes, int n_in,
                              void* d_out, int out_size, void* d_ws, size_t ws_size,
                              hipStream_t stream) {
    const float* x   = (const float*)d_in[0];
    const float* adj = (const float*)d_in[1];
    const float* W   = (const float*)d_in[2];
    float* out = (float*)d_out;
    (void)d_ws; (void)ws_size;   // workspace intentionally unused

    fused_kernel<<<NROWS / 4, 256, 0, stream>>>(x, adj, W, out);
}

// Round 2
// 1344.182 us; speedup vs baseline: 1.4729x; 1.4729x over previous
//
#include <hip/hip_runtime.h>
#include <math.h>

#define NROWS 16384
#define MINN 1e-15f
#define NITER (NROWS / 1024)

typedef float vf4 __attribute__((ext_vector_type(4)));

__device__ __forceinline__ float waveSum(float v) {
    #pragma unroll
    for (int m = 32; m >= 1; m >>= 1) v += __shfl_xor(v, m, 64);
    return v;
}

// Kernel 1: per row of x, compute ht = logmap0(proj(expmap0(logmap0(x) @ W^T)))
// One wave per row; W staged transposed in LDS (WT[d][k] = W[k][d]).
__global__ __launch_bounds__(256) void prep_kernel(
    const float* __restrict__ x, const float* __restrict__ W,
    float* __restrict__ ht)
{
    __shared__ float WT[64 * 64];
    for (int t = threadIdx.x; t < 64 * 64; t += 256) {
        int k = t >> 6, d = t & 63;
        WT[d * 64 + k] = W[t];   // broadcast reads later -> conflict-free
    }
    __syncthreads();
    const int lane = threadIdx.x & 63;
    const int row = blockIdx.x * 4 + (threadIdx.x >> 6);

    float xv = x[row * 64 + lane];
    // u = logmap0(x)
    float sq = (lane == 0) ? 0.f : xv * xv;
    float yn = fmaxf(sqrtf(waveSum(sq)), MINN);
    float theta = fmaxf(__shfl(xv, 0, 64), 1.0f + 1e-7f);
    float s = acoshf(theta) / yn;
    float u = (lane == 0) ? 0.f : s * xv;

    // h1[k] = sum_d u[d] * W[k][d]  (lane = k); u[0]==0 so start at d=1
    float h1 = 0.f;
    #pragma unroll
    for (int d = 1; d < 64; ++d)
        h1 = fmaf(__shfl(u, d, 64), WT[d * 64 + lane], h1);

    // ht = logmap0(proj(expmap0(h1)))
    float z = (lane == 0) ? 0.f : h1;
    float zn = fmaxf(sqrtf(waveSum(z * z)), MINN);
    float sh = sinhf(zn);
    float ey = sh * z / zn;                       // lane0 -> 0
    float s2 = waveSum(ey * ey);
    float first = sqrtf(fmaxf(1.f + s2, MINN));
    float ynb = fmaxf(sqrtf(s2), MINN);
    float th2 = fmaxf(first, 1.0f + 1e-7f);
    float coef = acoshf(th2) / ynb;
    float htv = (lane == 0) ? 0.f : coef * ey;
    ht[row * 64 + lane] = htv;
}

// Kernel 2: h2 = adj @ ht (sparse-aware stream) + fused epilogue.
// One wave per output row. Explicit 1-deep prefetch: while the ballot/scan
// phase (exec-dependent, compiler can't hoist loads above it) processes
// window i, window i+1's 4 KiB is already in flight -> wave keeps ~8 KiB
// outstanding instead of alternating 4 KiB / 0.
__global__ __launch_bounds__(256) void agg_kernel(
    const float* __restrict__ adj, const float* __restrict__ ht,
    float* __restrict__ out)
{
    const int lane = threadIdx.x & 63;
    const int row = blockIdx.x * 4 + (threadIdx.x >> 6);
    const float* arow = adj + (size_t)row * NROWS;

    const float* b0 = arow + lane * 4;
    vf4 c0 = __builtin_nontemporal_load((const vf4*)(b0 + 0));
    vf4 c1 = __builtin_nontemporal_load((const vf4*)(b0 + 256));
    vf4 c2 = __builtin_nontemporal_load((const vf4*)(b0 + 512));
    vf4 c3 = __builtin_nontemporal_load((const vf4*)(b0 + 768));

    float acc = 0.f;
    for (int it = 0; it < NITER; ++it) {
        vf4 n0, n1, n2, n3;
        const bool more = (it + 1 < NITER);
        if (more) {
            const float* nb = arow + (size_t)(it + 1) * 1024 + lane * 4;
            n0 = __builtin_nontemporal_load((const vf4*)(nb + 0));
            n1 = __builtin_nontemporal_load((const vf4*)(nb + 256));
            n2 = __builtin_nontemporal_load((const vf4*)(nb + 512));
            n3 = __builtin_nontemporal_load((const vf4*)(nb + 768));
        }
        #pragma unroll
        for (int w = 0; w < 4; ++w) {
            vf4 v = (w == 0) ? c0 : (w == 1) ? c1 : (w == 2) ? c2 : c3;
            unsigned int any = __float_as_uint(v.x) | __float_as_uint(v.y) |
                               __float_as_uint(v.z) | __float_as_uint(v.w);
            unsigned long long mask = __ballot(any != 0u);  // zeros are exact +0.0
            int jwin = it * 1024 + w * 256;
            while (mask) {
                int L = __ffsll((long long)mask) - 1;
                mask &= mask - 1;
                float a0 = __shfl(v.x, L, 64);
                float a1 = __shfl(v.y, L, 64);
                float a2 = __shfl(v.z, L, 64);
                float a3 = __shfl(v.w, L, 64);
                int jbase = jwin + L * 4;
                if (a0 != 0.f) acc = fmaf(a0, ht[(size_t)(jbase + 0) * 64 + lane], acc);
                if (a1 != 0.f) acc = fmaf(a1, ht[(size_t)(jbase + 1) * 64 + lane], acc);
                if (a2 != 0.f) acc = fmaf(a2, ht[(size_t)(jbase + 2) * 64 + lane], acc);
                if (a3 != 0.f) acc = fmaf(a3, ht[(size_t)(jbase + 3) * 64 + lane], acc);
            }
        }
        if (more) { c0 = n0; c1 = n1; c2 = n2; c3 = n3; }
    }

    // Epilogue (literal reference clamps; empty rows -> [1,0,...,0])
    float z = (lane == 0) ? 0.f : acc;
    float zn = fmaxf(sqrtf(waveSum(z * z)), MINN);
    float sh = sinhf(zn);
    float ey = sh * z / zn;
    float s2 = waveSum(ey * ey);
    float first = sqrtf(fmaxf(1.f + s2, MINN));
    float ynb = fmaxf(sqrtf(s2), MINN);
    float th2 = fmaxf(first, 1.0f + 1e-7f);
    float l = acoshf(th2) / ynb * ey;
    float xt = fmaxf(l, 0.f);
    if (lane == 0) xt = 0.f;
    float xn = fmaxf(sqrtf(waveSum(xt * xt)), MINN);
    float sh2 = sinhf(xn);
    float oy = sh2 * xt / xn;
    float o0 = sqrtf(fmaxf(1.f + waveSum(oy * oy), MINN));
    float outv = (lane == 0) ? o0 : oy;
    out[row * 64 + lane] = outv;
}

extern "C" void kernel_launch(void* const* d_in, const int* in_sizes, int n_in,
                              void* d_out, int out_size, void* d_ws, size_t ws_size,
                              hipStream_t stream) {
    const float* x   = (const float*)d_in[0];
    const float* adj = (const float*)d_in[1];
    const float* W   = (const float*)d_in[2];
    float* out = (float*)d_out;
    float* ht  = (float*)d_ws;   // 16384*64*4 = 4 MiB scratch

    prep_kernel<<<NROWS / 4, 256, 0, stream>>>(x, W, ht);
    agg_kernel<<<NROWS / 4, 256, 0, stream>>>(adj, ht, out);
}